// Round 2
// baseline (107.140 us; speedup 1.0000x reference)
//
#include <hip/hip_runtime.h>

typedef unsigned short u16;
typedef unsigned int u32;
typedef __attribute__((ext_vector_type(8))) short short8;
typedef __attribute__((ext_vector_type(4))) float f32x4;

__device__ __forceinline__ u16 f2bf(float f) {
    unsigned u = __float_as_uint(f);
    return (u16)((u + 0x7FFFu + ((u >> 16) & 1u)) >> 16);  // RNE
}
__device__ __forceinline__ u32 pack2(float a, float b) {
    return ((u32)f2bf(b) << 16) | (u32)f2bf(a);
}

// ---- DPP row-rotate helpers (16-lane rows == one 16x16 matrix group) ----
#define ROR1 0x121
#define ROR2 0x122
#define ROR4 0x124
#define ROR8 0x128
template<int C> __device__ __forceinline__ float dppf(float x) {
    int i = __float_as_int(x);
    return __int_as_float(__builtin_amdgcn_update_dpp(i, i, C, 0xF, 0xF, false));
}
template<int C> __device__ __forceinline__ int dppi(int x) {
    return __builtin_amdgcn_update_dpp(x, x, C, 0xF, 0xF, false);
}

// ---------------------------------------------------------------------------
// L1: fused build-X (from the reference's stack+reshape quirk) + GEMM +
// bias + leaky + bf16 store.  64 rows x 32-col tile, K=256.  Grid 128.
// ---------------------------------------------------------------------------
__global__ __launch_bounds__(256) void k_gemm_l1(
    const float* __restrict__ emb,   // [8][16][128]
    const float* __restrict__ W,     // [256][4096]
    const float* __restrict__ bias,  // [4096]
    u16* __restrict__ H)             // [64][4096] bf16 out
{
    __shared__ __align__(16) u16 Alds[64][136];
    __shared__ __align__(16) u16 Wlds[32][136];
    int tid = threadIdx.x;
    int wv = tid >> 6, lane = tid & 63, c = lane & 15, g = lane >> 4;
    int c0 = blockIdx.x * 32;
    f32x4 acc0 = {0.f,0.f,0.f,0.f}, acc1 = {0.f,0.f,0.f,0.f};

    for (int kc = 0; kc < 256; kc += 128) {
        {   // build+stage A[64][128]: X[r][e] = emb[2*(r&3)+(e>>7)][r>>2][e&127]
            int row = tid >> 2, seg = tid & 3;
            int b = 2 * (row & 3) + (kc >> 7), nd = row >> 2;
            const float4* src = (const float4*)(emb + (b * 16 + nd) * 128 + seg * 32);
            u32* dst = (u32*)&Alds[row][seg * 32];
            #pragma unroll
            for (int t = 0; t < 8; ++t) {
                float4 f = src[t];
                dst[2 * t]     = pack2(f.x, f.y);
                dst[2 * t + 1] = pack2(f.z, f.w);
            }
        }
        {   // stage W[128][32] fp32 -> Wlds[32][128] bf16 transposed
            int krow = tid >> 1, half = tid & 1;
            const float* src = W + (size_t)(kc + krow) * 4096 + c0 + half * 16;
            float4 p0 = ((const float4*)src)[0];
            float4 p1 = ((const float4*)src)[1];
            float4 p2 = ((const float4*)src)[2];
            float4 p3 = ((const float4*)src)[3];
            int cb = half * 16;
            Wlds[cb + 0][krow] = f2bf(p0.x);  Wlds[cb + 1][krow] = f2bf(p0.y);
            Wlds[cb + 2][krow] = f2bf(p0.z);  Wlds[cb + 3][krow] = f2bf(p0.w);
            Wlds[cb + 4][krow] = f2bf(p1.x);  Wlds[cb + 5][krow] = f2bf(p1.y);
            Wlds[cb + 6][krow] = f2bf(p1.z);  Wlds[cb + 7][krow] = f2bf(p1.w);
            Wlds[cb + 8][krow] = f2bf(p2.x);  Wlds[cb + 9][krow] = f2bf(p2.y);
            Wlds[cb + 10][krow] = f2bf(p2.z); Wlds[cb + 11][krow] = f2bf(p2.w);
            Wlds[cb + 12][krow] = f2bf(p3.x); Wlds[cb + 13][krow] = f2bf(p3.y);
            Wlds[cb + 14][krow] = f2bf(p3.z); Wlds[cb + 15][krow] = f2bf(p3.w);
        }
        __syncthreads();
        #pragma unroll
        for (int ks = 0; ks < 4; ++ks) {
            int kk = ks * 32 + g * 8;
            short8 a8 = *(const short8*)&Alds[wv * 16 + c][kk];
            short8 b0 = *(const short8*)&Wlds[c][kk];
            short8 b1 = *(const short8*)&Wlds[16 + c][kk];
            acc0 = __builtin_amdgcn_mfma_f32_16x16x32_bf16(a8, b0, acc0, 0, 0, 0);
            acc1 = __builtin_amdgcn_mfma_f32_16x16x32_bf16(a8, b1, acc1, 0, 0, 0);
        }
        __syncthreads();
    }
    int rbase = wv * 16 + g * 4;
    #pragma unroll
    for (int rr = 0; rr < 4; ++rr) {
        int col0 = c0 + c, col1 = c0 + 16 + c;
        float v0 = acc0[rr] + bias[col0]; v0 = (v0 >= 0.f) ? v0 : 0.01f * v0;
        float v1 = acc1[rr] + bias[col1]; v1 = (v1 >= 0.f) ? v1 : 0.01f * v1;
        H[(size_t)(rbase + rr) * 4096 + col0] = f2bf(v0);
        H[(size_t)(rbase + rr) * 4096 + col1] = f2bf(v1);
    }
}

// ---------------------------------------------------------------------------
// L2/L3: full-K GEMM, fused epilogue.  M-split x2 (32 rows) x 32-col tile.
// Grid 256 with XCD pair-swizzle: the two blocks sharing a W col-tile land
// on the same XCD (same d%8) so W is HBM-fetched once, second read L2-hits.
// ---------------------------------------------------------------------------
__global__ __launch_bounds__(256) void k_gemm_mid(
    const u16* __restrict__ A,       // [64][4096] bf16
    const float* __restrict__ W,     // [4096][4096]
    const float* __restrict__ bias,  // [4096]
    u16* __restrict__ H)             // [64][4096] bf16 out
{
    __shared__ __align__(16) u16 Alds[32][136];
    __shared__ __align__(16) u16 Wlds[32][136];
    int d = blockIdx.x;
    int p = ((d >> 4) << 3) + (d & 7);   // col-tile [0,128)
    int q = (d >> 3) & 1;                // M-half
    int c0 = p * 32, r0 = q * 32;
    int tid = threadIdx.x;
    int wv = tid >> 6, lane = tid & 63, c = lane & 15, g = lane >> 4;
    int wrow = (wv & 1) * 16, wcol = (wv >> 1) * 16;
    f32x4 acc = {0.f,0.f,0.f,0.f};

    for (int kc = 0; kc < 4096; kc += 128) {
        {   // stage A[32][128] bf16 (32B/thread)
            int row = tid >> 3, seg = tid & 7;
            const uint4* src = (const uint4*)(A + (size_t)(r0 + row) * 4096 + kc + seg * 16);
            uint4* dst = (uint4*)&Alds[row][seg * 16];
            dst[0] = src[0];
            dst[1] = src[1];
        }
        {   // stage W[128][32] fp32 -> Wlds[32][128] bf16 transposed
            int krow = tid >> 1, half = tid & 1;
            const float* src = W + (size_t)(kc + krow) * 4096 + c0 + half * 16;
            float4 p0 = ((const float4*)src)[0];
            float4 p1 = ((const float4*)src)[1];
            float4 p2 = ((const float4*)src)[2];
            float4 p3 = ((const float4*)src)[3];
            int cb = half * 16;
            Wlds[cb + 0][krow] = f2bf(p0.x);  Wlds[cb + 1][krow] = f2bf(p0.y);
            Wlds[cb + 2][krow] = f2bf(p0.z);  Wlds[cb + 3][krow] = f2bf(p0.w);
            Wlds[cb + 4][krow] = f2bf(p1.x);  Wlds[cb + 5][krow] = f2bf(p1.y);
            Wlds[cb + 6][krow] = f2bf(p1.z);  Wlds[cb + 7][krow] = f2bf(p1.w);
            Wlds[cb + 8][krow] = f2bf(p2.x);  Wlds[cb + 9][krow] = f2bf(p2.y);
            Wlds[cb + 10][krow] = f2bf(p2.z); Wlds[cb + 11][krow] = f2bf(p2.w);
            Wlds[cb + 12][krow] = f2bf(p3.x); Wlds[cb + 13][krow] = f2bf(p3.y);
            Wlds[cb + 14][krow] = f2bf(p3.z); Wlds[cb + 15][krow] = f2bf(p3.w);
        }
        __syncthreads();
        #pragma unroll
        for (int ks = 0; ks < 4; ++ks) {
            int kk = ks * 32 + g * 8;
            short8 a8 = *(const short8*)&Alds[wrow + c][kk];
            short8 b8 = *(const short8*)&Wlds[wcol + c][kk];
            acc = __builtin_amdgcn_mfma_f32_16x16x32_bf16(a8, b8, acc, 0, 0, 0);
        }
        __syncthreads();
    }
    #pragma unroll
    for (int rr = 0; rr < 4; ++rr) {
        int grow = r0 + wrow + g * 4 + rr;
        int gcol = c0 + wcol + c;
        float v = acc[rr] + bias[gcol];
        v = (v >= 0.f) ? v : 0.01f * v;
        H[(size_t)grow * 4096 + gcol] = f2bf(v);
    }
}

// ---------------------------------------------------------------------------
// L4: split-K partials (round-1 kernel, unchanged).  Grid (8, ksplit).
// ---------------------------------------------------------------------------
__global__ __launch_bounds__(256) void k_gemm(
    const u16* __restrict__ A, const float* __restrict__ W,
    float* __restrict__ Cp, int K, int N, int kchunk)
{
    __shared__ __align__(16) u16 Alds[64][136];
    __shared__ __align__(16) u16 Wlds[32][136];
    int tid = threadIdx.x;
    int wv = tid >> 6, lane = tid & 63, c = lane & 15, g = lane >> 4;
    int c0 = blockIdx.x * 32;
    int k0 = blockIdx.y * kchunk;
    f32x4 acc0 = {0.f,0.f,0.f,0.f}, acc1 = {0.f,0.f,0.f,0.f};

    for (int kc = 0; kc < kchunk; kc += 128) {
        {
            int row = tid >> 2, seg = tid & 3;
            const uint4* src = (const uint4*)(A + (size_t)row * K + k0 + kc + seg * 32);
            uint4* dst = (uint4*)&Alds[row][seg * 32];
            dst[0] = src[0]; dst[1] = src[1]; dst[2] = src[2]; dst[3] = src[3];
        }
        {
            int krow = tid >> 1, half = tid & 1;
            const float* src = W + (size_t)(k0 + kc + krow) * N + c0 + half * 16;
            float4 p0 = ((const float4*)src)[0];
            float4 p1 = ((const float4*)src)[1];
            float4 p2 = ((const float4*)src)[2];
            float4 p3 = ((const float4*)src)[3];
            int cb = half * 16;
            Wlds[cb + 0][krow] = f2bf(p0.x);  Wlds[cb + 1][krow] = f2bf(p0.y);
            Wlds[cb + 2][krow] = f2bf(p0.z);  Wlds[cb + 3][krow] = f2bf(p0.w);
            Wlds[cb + 4][krow] = f2bf(p1.x);  Wlds[cb + 5][krow] = f2bf(p1.y);
            Wlds[cb + 6][krow] = f2bf(p1.z);  Wlds[cb + 7][krow] = f2bf(p1.w);
            Wlds[cb + 8][krow] = f2bf(p2.x);  Wlds[cb + 9][krow] = f2bf(p2.y);
            Wlds[cb + 10][krow] = f2bf(p2.z); Wlds[cb + 11][krow] = f2bf(p2.w);
            Wlds[cb + 12][krow] = f2bf(p3.x); Wlds[cb + 13][krow] = f2bf(p3.y);
            Wlds[cb + 14][krow] = f2bf(p3.z); Wlds[cb + 15][krow] = f2bf(p3.w);
        }
        __syncthreads();
        #pragma unroll
        for (int ks = 0; ks < 4; ++ks) {
            int kk = ks * 32 + g * 8;
            short8 a8 = *(const short8*)&Alds[wv * 16 + c][kk];
            short8 b0 = *(const short8*)&Wlds[c][kk];
            short8 b1 = *(const short8*)&Wlds[16 + c][kk];
            acc0 = __builtin_amdgcn_mfma_f32_16x16x32_bf16(a8, b0, acc0, 0, 0, 0);
            acc1 = __builtin_amdgcn_mfma_f32_16x16x32_bf16(a8, b1, acc1, 0, 0, 0);
        }
        __syncthreads();
    }
    float* out = Cp + (size_t)blockIdx.y * 64 * N;
    int rbase = wv * 16 + g * 4;
    #pragma unroll
    for (int rr = 0; rr < 4; ++rr) {
        out[(size_t)(rbase + rr) * N + c0 + c]      = acc0[rr];
        out[(size_t)(rbase + rr) * N + c0 + 16 + c] = acc1[rr];
    }
}

// ---------------------------------------------------------------------------
// Fused: Cp-reduce + bias + leaky + sigmoid -> pol (in LDS, two halves),
// then 50 power iterations entirely on the VALU via DPP row-rotates
// (no LDS-pipe cross-lane traffic), then the factored output reduction.
// Normalization (scale cancels in output ratios; matrices positive) is a
// ror-8/4/2/1 sum every 8th iteration.  Mr[k] gather uses an integer index
// rotated by the SAME DPP op as v, so hardware rotate direction is moot.
// ---------------------------------------------------------------------------
__global__ __launch_bounds__(1024) void k_power_out(
    const float* __restrict__ Cp,    // [8][64][256] partials
    const float* __restrict__ bias,  // [256]
    const float* __restrict__ Ts,    // [8][16][16]
    float* __restrict__ out)         // [8][16]
{
    __shared__ float pol_lds[8192];  // one 32-matrix half at a time
    __shared__ float w_lds[64][16];
    __shared__ float Ts_lds[2048];
    __shared__ float Cmat[8][16];

    int tid = threadIdx.x;
    int m = tid >> 4, r = tid & 15;

    Ts_lds[tid] = Ts[tid];
    Ts_lds[tid + 1024] = Ts[tid + 1024];

    float Mr[8], Ms[8];
    for (int h = 0; h < 2; ++h) {
        // reduce matrices [32h, 32h+32): 8192 floats, 8 per thread
        int base = tid * 8;
        int g0 = h * 8192 + base;
        float4 sA = ((const float4*)(Cp + g0))[0];
        float4 sB = ((const float4*)(Cp + g0))[1];
        #pragma unroll
        for (int ks = 1; ks < 8; ++ks) {
            const float4* p4 = (const float4*)(Cp + ks * 16384 + g0);
            sA.x += p4[0].x; sA.y += p4[0].y; sA.z += p4[0].z; sA.w += p4[0].w;
            sB.x += p4[1].x; sB.y += p4[1].y; sB.z += p4[1].z; sB.w += p4[1].w;
        }
        int col0 = base & 255;
        const float4* bp = (const float4*)(bias + col0);
        float4 bA = bp[0], bB = bp[1];
        float vals[8] = {sA.x + bA.x, sA.y + bA.y, sA.z + bA.z, sA.w + bA.w,
                         sB.x + bB.x, sB.y + bB.y, sB.z + bB.z, sB.w + bB.w};
        #pragma unroll
        for (int t = 0; t < 8; ++t) {
            float a = vals[t];
            a = (a >= 0.f) ? a : 0.01f * a;
            pol_lds[base + t] = 1.0f / (1.0f + __expf(-a));
        }
        __syncthreads();
        if ((m >> 5) == h) {    // group-uniform: whole 16-lane rows in/out
            int mb = (m & 31) * 256 + r * 16;
            int idx = r;
            #pragma unroll
            for (int k = 0; k < 8; ++k) { Mr[k] = pol_lds[mb + idx]; idx = dppi<ROR1>(idx); }
            #pragma unroll
            for (int k = 0; k < 8; ++k) { Ms[k] = pol_lds[mb + idx]; idx = dppi<ROR1>(idx); }
        }
        __syncthreads();
    }

    // 50 power iterations, two independent rotate chains for ILP
    float v = 1.0f;
    #pragma unroll 1
    for (int it = 0; it < 50; ++it) {
        float va = v, vb = dppf<ROR8>(v);
        float w = 0.f, w2 = 0.f;
        #pragma unroll
        for (int k = 0; k < 8; ++k) {
            w  = fmaf(Mr[k], va, w);
            w2 = fmaf(Ms[k], vb, w2);
            if (k < 7) { va = dppf<ROR1>(va); vb = dppf<ROR1>(vb); }
        }
        w += w2;
        if ((it & 7) == 7) {   // cheap positive-sum renorm; scale cancels later
            float s = w;
            s += dppf<ROR8>(s); s += dppf<ROR4>(s);
            s += dppf<ROR2>(s); s += dppf<ROR1>(s);
            w *= 1.0f / s;
        }
        v = w;
    }
    w_lds[m][r] = v;
    __syncthreads();

    if (tid < 128) {
        int b = tid >> 4, x = tid & 15;
        float s = 0.f;
        if (b < 4) {                             // R[b][s=x] = sum_t Ts[b][x][t]
            const float* row = &Ts_lds[(b * 16 + x) * 16];
            #pragma unroll
            for (int t = 0; t < 16; ++t) s += row[t];
        } else {                                 // C[b][t=x]
            int j = b - 4;
            #pragma unroll
            for (int si = 0; si < 16; ++si)
                s += Ts_lds[(b * 16 + si) * 16 + x] / w_lds[x * 4 + j][si];
        }
        Cmat[b][x] = s;
    }
    __syncthreads();

    if (tid < 128) {
        int b = tid >> 4, n = tid & 15;
        float o = 0.f;
        if (b < 4) {
            #pragma unroll
            for (int si = 0; si < 16; ++si) {
                const float* wr = w_lds[si * 4 + b];
                o += wr[n] / wr[si] * Cmat[b][si];
            }
        } else {
            int j = b - 4;
            #pragma unroll
            for (int t = 0; t < 16; ++t)
                o += w_lds[t * 4 + j][n] * Cmat[b][t];
        }
        out[b * 16 + n] = o;
    }
}

// ---------------------------------------------------------------------------
extern "C" void kernel_launch(void* const* d_in, const int* in_sizes, int n_in,
                              void* d_out, int out_size, void* d_ws, size_t ws_size,
                              hipStream_t stream)
{
    const float* emb = (const float*)d_in[0];
    const float* Ts  = (const float*)d_in[2];
    const float* W1  = (const float*)d_in[3];  const float* b1 = (const float*)d_in[4];
    const float* W2  = (const float*)d_in[5];  const float* b2 = (const float*)d_in[6];
    const float* W3  = (const float*)d_in[7];  const float* b3 = (const float*)d_in[8];
    const float* W4  = (const float*)d_in[9];  const float* b4 = (const float*)d_in[10];
    float* outp = (float*)d_out;

    char* ws = (char*)d_ws;
    u16*   Ha = (u16*)(ws + 0);            // 512 KB  [64][4096] bf16
    u16*   Hb = (u16*)(ws + 524288);       // 512 KB  [64][4096] bf16
    float* Cp = (float*)(ws + 1048576);    // 512 KB  [8][64][256] fp32

    k_gemm_l1 <<<128, 256, 0, stream>>>(emb, W1, b1, Ha);
    k_gemm_mid<<<256, 256, 0, stream>>>(Ha, W2, b2, Hb);
    k_gemm_mid<<<256, 256, 0, stream>>>(Hb, W3, b3, Ha);
    k_gemm    <<<dim3(8, 8), 256, 0, stream>>>(Ha, W4, Cp, 4096, 256, 512);
    k_power_out<<<1, 1024, 0, stream>>>(Cp, b4, Ts, outp);

    (void)in_sizes; (void)n_in; (void)out_size; (void)ws_size;
}

// Round 3
// 94.260 us; speedup vs baseline: 1.1366x; 1.1366x over previous
//
#include <hip/hip_runtime.h>

typedef unsigned short u16;
typedef unsigned int u32;
typedef __attribute__((ext_vector_type(8))) short short8;
typedef __attribute__((ext_vector_type(4))) float f32x4;

__device__ __forceinline__ u16 f2bf(float f) {
    unsigned u = __float_as_uint(f);
    return (u16)((u + 0x7FFFu + ((u >> 16) & 1u)) >> 16);  // RNE
}
__device__ __forceinline__ u32 pack2(float a, float b) {
    return ((u32)f2bf(b) << 16) | (u32)f2bf(a);
}

// ---- DPP row-rotate helpers (16-lane rows) ----
#define ROR1 0x121
#define ROR2 0x122
#define ROR4 0x124
#define ROR8 0x128
template<int C> __device__ __forceinline__ float dppf(float x) {
    int i = __float_as_int(x);
    return __int_as_float(__builtin_amdgcn_update_dpp(i, i, C, 0xF, 0xF, false));
}
template<int C> __device__ __forceinline__ int dppi(int x) {
    return __builtin_amdgcn_update_dpp(x, x, C, 0xF, 0xF, false);
}

// ---------------------------------------------------------------------------
// W-staging: chunk W[k0..k0+128][c0..c0+32] fp32 -> Wlds[32][136] bf16 [col][k].
// Wave wv owns 8 cols; lane owns a k-row PAIR; pack 2 k's per ds_write_b32 at
// u32 word col*68+lane -> banks = lane%32 (2-way, free; was 4-way scalar u16).
// ---------------------------------------------------------------------------
__device__ __forceinline__ void stage_w(const float* __restrict__ W, int N,
                                        int krow0, int c0, int wv, int lane,
                                        u16 (*Wlds)[136])
{
    int cb = wv * 8;
    const float* s0 = W + (size_t)(krow0 + 2 * lane) * N + c0 + cb;
    float4 r0a = ((const float4*)s0)[0];
    float4 r0b = ((const float4*)s0)[1];
    const float* s1 = s0 + N;
    float4 r1a = ((const float4*)s1)[0];
    float4 r1b = ((const float4*)s1)[1];
    u32* wb = (u32*)&Wlds[0][0];
    wb[(cb + 0) * 68 + lane] = pack2(r0a.x, r1a.x);
    wb[(cb + 1) * 68 + lane] = pack2(r0a.y, r1a.y);
    wb[(cb + 2) * 68 + lane] = pack2(r0a.z, r1a.z);
    wb[(cb + 3) * 68 + lane] = pack2(r0a.w, r1a.w);
    wb[(cb + 4) * 68 + lane] = pack2(r0b.x, r1b.x);
    wb[(cb + 5) * 68 + lane] = pack2(r0b.y, r1b.y);
    wb[(cb + 6) * 68 + lane] = pack2(r0b.z, r1b.z);
    wb[(cb + 7) * 68 + lane] = pack2(r0b.w, r1b.w);
}

// ---------------------------------------------------------------------------
// Generic split-K GEMM: Cp[by][64][N] += A[64][k-slice] @ W[k-slice][32-col tile]
// grid (N/32, ksplit), 256 threads.  Used for L2, L3, L4.
// ---------------------------------------------------------------------------
__global__ __launch_bounds__(256) void k_gemm(
    const u16* __restrict__ A,   // [64][K] bf16
    const float* __restrict__ W, // [K][N] fp32
    float* __restrict__ Cp,      // [ksplit][64][N] fp32 partials
    int K, int N, int kchunk)
{
    __shared__ __align__(16) u16 Alds[64][136];
    __shared__ __align__(16) u16 Wlds[32][136];
    int tid = threadIdx.x;
    int wv = tid >> 6, lane = tid & 63, c = lane & 15, g = lane >> 4;
    int c0 = blockIdx.x * 32;
    int k0 = blockIdx.y * kchunk;
    f32x4 acc0 = {0.f,0.f,0.f,0.f}, acc1 = {0.f,0.f,0.f,0.f};

    for (int kc = 0; kc < kchunk; kc += 128) {
        {   // stage A[64][128] bf16, 64B/thread
            int row = tid >> 2, seg = tid & 3;
            const uint4* src = (const uint4*)(A + (size_t)row * K + k0 + kc + seg * 32);
            uint4* dst = (uint4*)&Alds[row][seg * 32];
            dst[0] = src[0]; dst[1] = src[1]; dst[2] = src[2]; dst[3] = src[3];
        }
        stage_w(W, N, k0 + kc, c0, wv, lane, Wlds);
        __syncthreads();
        #pragma unroll
        for (int ks = 0; ks < 4; ++ks) {
            int kk = ks * 32 + g * 8;
            short8 a8 = *(const short8*)&Alds[wv * 16 + c][kk];
            short8 b0 = *(const short8*)&Wlds[c][kk];
            short8 b1 = *(const short8*)&Wlds[16 + c][kk];
            acc0 = __builtin_amdgcn_mfma_f32_16x16x32_bf16(a8, b0, acc0, 0, 0, 0);
            acc1 = __builtin_amdgcn_mfma_f32_16x16x32_bf16(a8, b1, acc1, 0, 0, 0);
        }
        __syncthreads();
    }
    float* out = Cp + (size_t)blockIdx.y * 64 * N;
    int rbase = wv * 16 + g * 4;
    #pragma unroll
    for (int rr = 0; rr < 4; ++rr) {
        out[(size_t)(rbase + rr) * N + c0 + c]      = acc0[rr];
        out[(size_t)(rbase + rr) * N + c0 + 16 + c] = acc1[rr];
    }
}

// ---------------------------------------------------------------------------
// L1: fused build-X + GEMM, split-K x2.  grid (128, 2).  K-half = blockIdx.y.
// X[r][e] = emb[2*(r&3)+(e>=128)][r>>2][e&127]  (the stack+reshape quirk).
// ---------------------------------------------------------------------------
__global__ __launch_bounds__(256) void k_gemm_l1(
    const float* __restrict__ emb,   // [8][16][128]
    const float* __restrict__ W,     // [256][4096]
    float* __restrict__ Cp)          // [2][64][4096]
{
    __shared__ __align__(16) u16 Alds[64][136];
    __shared__ __align__(16) u16 Wlds[32][136];
    int tid = threadIdx.x;
    int wv = tid >> 6, lane = tid & 63, c = lane & 15, g = lane >> 4;
    int c0 = blockIdx.x * 32;
    int half = blockIdx.y;               // k in [128*half, 128*half+128)
    f32x4 acc0 = {0.f,0.f,0.f,0.f}, acc1 = {0.f,0.f,0.f,0.f};

    {   // build+stage A[64][128]
        int row = tid >> 2, seg = tid & 3;
        int b = 2 * (row & 3) + half, nd = row >> 2;
        const float4* src = (const float4*)(emb + (b * 16 + nd) * 128 + seg * 32);
        u32* dst = (u32*)&Alds[row][seg * 32];
        #pragma unroll
        for (int t = 0; t < 8; ++t) {
            float4 f = src[t];
            dst[2 * t]     = pack2(f.x, f.y);
            dst[2 * t + 1] = pack2(f.z, f.w);
        }
    }
    stage_w(W, 4096, half * 128, c0, wv, lane, Wlds);
    __syncthreads();
    #pragma unroll
    for (int ks = 0; ks < 4; ++ks) {
        int kk = ks * 32 + g * 8;
        short8 a8 = *(const short8*)&Alds[wv * 16 + c][kk];
        short8 b0 = *(const short8*)&Wlds[c][kk];
        short8 b1 = *(const short8*)&Wlds[16 + c][kk];
        acc0 = __builtin_amdgcn_mfma_f32_16x16x32_bf16(a8, b0, acc0, 0, 0, 0);
        acc1 = __builtin_amdgcn_mfma_f32_16x16x32_bf16(a8, b1, acc1, 0, 0, 0);
    }
    float* out = Cp + (size_t)half * 64 * 4096;
    int rbase = wv * 16 + g * 4;
    #pragma unroll
    for (int rr = 0; rr < 4; ++rr) {
        out[(size_t)(rbase + rr) * 4096 + c0 + c]      = acc0[rr];
        out[(size_t)(rbase + rr) * 4096 + c0 + 16 + c] = acc1[rr];
    }
}

// ---------------------------------------------------------------------------
// Reduce split-K partials + bias + leaky; mode 0 -> bf16 H, mode 1 ->
// sigmoid(leaky) fp32.  grid = 64*N/256 blocks.
// ---------------------------------------------------------------------------
__global__ void k_reduce(const float* __restrict__ Cp, const float* __restrict__ bias,
                         u16* __restrict__ Hb, float* __restrict__ Pf,
                         int N, int ksplit, int mode)
{
    int idx = blockIdx.x * 256 + threadIdx.x;
    int col = idx & (N - 1);
    float s = bias[col];
    for (int k = 0; k < ksplit; ++k) s += Cp[(size_t)k * 64 * N + idx];
    float a = (s >= 0.f) ? s : 0.01f * s;
    if (mode == 0) Hb[idx] = f2bf(a);
    else           Pf[idx] = 1.0f / (1.0f + __expf(-a));
}

// ---------------------------------------------------------------------------
// 50 power iterations (VALU/DPP only) + factored output reduction.
// ---------------------------------------------------------------------------
__global__ __launch_bounds__(1024) void k_power_out(
    const float* __restrict__ pol,  // [64][16][16] fp32 (post-sigmoid)
    const float* __restrict__ Ts,   // [8][16][16]
    float* __restrict__ out)        // [8][16]
{
    __shared__ float pol_lds[16384];
    __shared__ float w_lds[64][16];
    __shared__ float Ts_lds[2048];
    __shared__ float Cmat[8][16];

    int tid = threadIdx.x;
    int m = tid >> 4, r = tid & 15;

    {   // stage all 64 matrices (64 KB) to LDS
        const float4* p4 = (const float4*)(pol + tid * 16);
        float4* q4 = (float4*)&pol_lds[tid * 16];
        q4[0] = p4[0]; q4[1] = p4[1]; q4[2] = p4[2]; q4[3] = p4[3];
    }
    Ts_lds[tid] = Ts[tid];
    Ts_lds[tid + 1024] = Ts[tid + 1024];
    __syncthreads();

    // gather row r of matrix m with DPP-rotated index (matches va rotation)
    float Mr[8], Ms[8];
    {
        int mb = m * 256 + r * 16;
        int idx = r;
        #pragma unroll
        for (int k = 0; k < 8; ++k) { Mr[k] = pol_lds[mb + idx]; idx = dppi<ROR1>(idx); }
        #pragma unroll
        for (int k = 0; k < 8; ++k) { Ms[k] = pol_lds[mb + idx]; idx = dppi<ROR1>(idx); }
    }

    float v = 1.0f;
    #pragma unroll 1
    for (int it = 0; it < 50; ++it) {
        float va = v, vb = dppf<ROR8>(v);
        float w = 0.f, w2 = 0.f;
        #pragma unroll
        for (int k = 0; k < 8; ++k) {
            w  = fmaf(Mr[k], va, w);
            w2 = fmaf(Ms[k], vb, w2);
            if (k < 7) { va = dppf<ROR1>(va); vb = dppf<ROR1>(vb); }
        }
        w += w2;
        if ((it & 7) == 7) {   // positive-sum renorm; scale cancels in output
            float s = w;
            s += dppf<ROR8>(s); s += dppf<ROR4>(s);
            s += dppf<ROR2>(s); s += dppf<ROR1>(s);
            w *= 1.0f / s;
        }
        v = w;
    }
    w_lds[m][r] = v;
    __syncthreads();

    if (tid < 128) {
        int b = tid >> 4, x = tid & 15;
        float s = 0.f;
        if (b < 4) {                             // R[b][s=x] = sum_t Ts[b][x][t]
            const float* row = &Ts_lds[(b * 16 + x) * 16];
            #pragma unroll
            for (int t = 0; t < 16; ++t) s += row[t];
        } else {                                 // C[b][t=x]
            int j = b - 4;
            #pragma unroll
            for (int si = 0; si < 16; ++si)
                s += Ts_lds[(b * 16 + si) * 16 + x] / w_lds[x * 4 + j][si];
        }
        Cmat[b][x] = s;
    }
    __syncthreads();

    if (tid < 128) {
        int b = tid >> 4, n = tid & 15;
        float o = 0.f;
        if (b < 4) {
            #pragma unroll
            for (int si = 0; si < 16; ++si) {
                const float* wr = w_lds[si * 4 + b];
                o += wr[n] / wr[si] * Cmat[b][si];
            }
        } else {
            int j = b - 4;
            #pragma unroll
            for (int t = 0; t < 16; ++t)
                o += w_lds[t * 4 + j][n] * Cmat[b][t];
        }
        out[b * 16 + n] = o;
    }
}

// ---------------------------------------------------------------------------
extern "C" void kernel_launch(void* const* d_in, const int* in_sizes, int n_in,
                              void* d_out, int out_size, void* d_ws, size_t ws_size,
                              hipStream_t stream)
{
    const float* emb = (const float*)d_in[0];
    const float* Ts  = (const float*)d_in[2];
    const float* W1  = (const float*)d_in[3];  const float* b1 = (const float*)d_in[4];
    const float* W2  = (const float*)d_in[5];  const float* b2 = (const float*)d_in[6];
    const float* W3  = (const float*)d_in[7];  const float* b3 = (const float*)d_in[8];
    const float* W4  = (const float*)d_in[9];  const float* b4 = (const float*)d_in[10];
    float* outp = (float*)d_out;

    char* ws = (char*)d_ws;
    u16*   Ha  = (u16*)(ws + 0);             // 512 KB  [64][4096] bf16
    u16*   Hb  = (u16*)(ws + 524288);        // 512 KB  [64][4096] bf16
    float* pol = (float*)(ws + 1048576);     //  64 KB  [64][16][16] fp32
    float* Cp  = (float*)(ws + 1114112);     //  KS MB  split-K partials

    // adaptive mid-layer ksplit: largest KS with 1.0625MB + KS*1MB <= ws_size
    int KS = 16;
    while (KS > 2 && (size_t)1114112 + (size_t)KS * 1048576 > ws_size) KS >>= 1;
    int kchunk = 4096 / KS;

    // L1: X(64x256) @ W1 -> Cp[2]; reduce -> Ha
    k_gemm_l1<<<dim3(128, 2), 256, 0, stream>>>(emb, W1, Cp);
    k_reduce<<<1024, 256, 0, stream>>>(Cp, b1, Ha, nullptr, 4096, 2, 0);

    // L2: Ha @ W2 -> Cp[KS]; reduce -> Hb
    k_gemm<<<dim3(128, KS), 256, 0, stream>>>(Ha, W2, Cp, 4096, 4096, kchunk);
    k_reduce<<<1024, 256, 0, stream>>>(Cp, b2, Hb, nullptr, 4096, KS, 0);

    // L3: Hb @ W3 -> Cp[KS]; reduce -> Ha
    k_gemm<<<dim3(128, KS), 256, 0, stream>>>(Hb, W3, Cp, 4096, 4096, kchunk);
    k_reduce<<<1024, 256, 0, stream>>>(Cp, b3, Ha, nullptr, 4096, KS, 0);

    // L4: Ha @ W4(4096x256) -> Cp[32]; reduce(+sigmoid) -> pol
    k_gemm<<<dim3(8, 32), 256, 0, stream>>>(Ha, W4, Cp, 4096, 256, 128);
    k_reduce<<<64, 256, 0, stream>>>(Cp, b4, nullptr, pol, 256, 32, 1);

    // Power iteration + factored output
    k_power_out<<<1, 1024, 0, stream>>>(pol, Ts, outp);

    (void)in_sizes; (void)n_in; (void)out_size; (void)ws_size;
}

// Round 4
// 85.733 us; speedup vs baseline: 1.2497x; 1.0995x over previous
//
#include <hip/hip_runtime.h>
#include <hip/hip_cooperative_groups.h>

namespace cg = cooperative_groups;

typedef unsigned short u16;
typedef unsigned int u32;
typedef __attribute__((ext_vector_type(8))) short short8;
typedef __attribute__((ext_vector_type(4))) float f32x4;

__device__ __forceinline__ u16 f2bf(float f) {
    unsigned u = __float_as_uint(f);
    return (u16)((u + 0x7FFFu + ((u >> 16) & 1u)) >> 16);  // RNE
}
__device__ __forceinline__ u32 pack2(float a, float b) {
    return ((u32)f2bf(b) << 16) | (u32)f2bf(a);
}

// ---- DPP row-rotate helpers (16-lane rows) ----
#define ROR1 0x121
#define ROR2 0x122
#define ROR4 0x124
#define ROR8 0x128
template<int C> __device__ __forceinline__ float dppf(float x) {
    int i = __float_as_int(x);
    return __int_as_float(__builtin_amdgcn_update_dpp(i, i, C, 0xF, 0xF, false));
}
template<int C> __device__ __forceinline__ int dppi(int x) {
    return __builtin_amdgcn_update_dpp(x, x, C, 0xF, 0xF, false);
}

// ---------------------------------------------------------------------------
// Pipelined GEMM slice: C[64][c0..c0+32) += A[64][k0..k0+128*nchunk) @ W[..]
// Global loads for chunk ch+1 issue right after the first barrier of chunk ch,
// hiding HBM latency under MFMA + second barrier + next ds_write wait.
// ---------------------------------------------------------------------------
__device__ __forceinline__ void gemm_slice(
    const u16* __restrict__ A, const float* __restrict__ W,
    float* __restrict__ outC, int K, int N, int c0, int k0, int nchunk,
    u16 (*Alds)[136], u16 (*Wlds)[136], int tid)
{
    int wv = tid >> 6, lane = tid & 63, c = lane & 15, g = lane >> 4;
    int arow = tid >> 2, aseg = tid & 3;
    int cb = wv * 8;
    f32x4 acc0 = {0.f,0.f,0.f,0.f}, acc1 = {0.f,0.f,0.f,0.f};

    uint4 ar0, ar1, ar2, ar3;
    float4 w0, w1, w2, w3;
    {   // prologue: chunk 0 loads
        const uint4* asrc = (const uint4*)(A + (size_t)arow * K + k0 + aseg * 32);
        ar0 = asrc[0]; ar1 = asrc[1]; ar2 = asrc[2]; ar3 = asrc[3];
        const float* s0 = W + (size_t)(k0 + 2 * lane) * N + c0 + cb;
        w0 = ((const float4*)s0)[0]; w1 = ((const float4*)s0)[1];
        const float* s1 = s0 + N;
        w2 = ((const float4*)s1)[0]; w3 = ((const float4*)s1)[1];
    }
    for (int ch = 0; ch < nchunk; ++ch) {
        {   // ds_write staged registers
            uint4* dst = (uint4*)&Alds[arow][aseg * 32];
            dst[0] = ar0; dst[1] = ar1; dst[2] = ar2; dst[3] = ar3;
            u32* wb = (u32*)&Wlds[0][0];
            wb[(cb + 0) * 68 + lane] = pack2(w0.x, w2.x);
            wb[(cb + 1) * 68 + lane] = pack2(w0.y, w2.y);
            wb[(cb + 2) * 68 + lane] = pack2(w0.z, w2.z);
            wb[(cb + 3) * 68 + lane] = pack2(w0.w, w2.w);
            wb[(cb + 4) * 68 + lane] = pack2(w1.x, w3.x);
            wb[(cb + 5) * 68 + lane] = pack2(w1.y, w3.y);
            wb[(cb + 6) * 68 + lane] = pack2(w1.z, w3.z);
            wb[(cb + 7) * 68 + lane] = pack2(w1.w, w3.w);
        }
        __syncthreads();
        if (ch + 1 < nchunk) {   // prefetch next chunk (overlaps MFMA below)
            int kn = k0 + (ch + 1) * 128;
            const uint4* asrc = (const uint4*)(A + (size_t)arow * K + kn + aseg * 32);
            ar0 = asrc[0]; ar1 = asrc[1]; ar2 = asrc[2]; ar3 = asrc[3];
            const float* s0 = W + (size_t)(kn + 2 * lane) * N + c0 + cb;
            w0 = ((const float4*)s0)[0]; w1 = ((const float4*)s0)[1];
            const float* s1 = s0 + N;
            w2 = ((const float4*)s1)[0]; w3 = ((const float4*)s1)[1];
        }
        #pragma unroll
        for (int ks = 0; ks < 4; ++ks) {
            int kk = ks * 32 + g * 8;
            short8 a8 = *(const short8*)&Alds[wv * 16 + c][kk];
            short8 b0 = *(const short8*)&Wlds[c][kk];
            short8 b1 = *(const short8*)&Wlds[16 + c][kk];
            acc0 = __builtin_amdgcn_mfma_f32_16x16x32_bf16(a8, b0, acc0, 0, 0, 0);
            acc1 = __builtin_amdgcn_mfma_f32_16x16x32_bf16(a8, b1, acc1, 0, 0, 0);
        }
        __syncthreads();
    }
    int rbase = wv * 16 + g * 4;
    #pragma unroll
    for (int rr = 0; rr < 4; ++rr) {
        outC[(size_t)(rbase + rr) * N + c0 + c]      = acc0[rr];
        outC[(size_t)(rbase + rr) * N + c0 + 16 + c] = acc1[rr];
    }
}

// ---------------------------------------------------------------------------
// Cooperative mega-kernel: all 9 phases, 8 grid syncs, zero launch gaps.
// Grid 1024 x 256 (4 blocks/CU).  LDS 26112 B (union'd across phases).
// ---------------------------------------------------------------------------
struct MegaP {
    const float *emb, *Ts, *W1, *b1, *W2, *b2, *W3, *b3, *W4, *b4;
    float* out;
    u16 *Ha, *Hb;
    float *Cp, *wvec;
};

__global__ __launch_bounds__(256) void mega(MegaP p)
{
    __shared__ __align__(16) u16 Alds[64][136];   // 17408 B
    __shared__ __align__(16) u16 Wlds[32][136];   //  8704 B
    cg::grid_group grid = cg::this_grid();
    int bid = blockIdx.x, tid = threadIdx.x;
    int wv = tid >> 6, lane = tid & 63, c = lane & 15, g = lane >> 4;

    // ---- P0: L1 fused build-X + GEMM (256 tiles: 128 col-tiles x 2 k-halves)
    if (bid < 256) {
        int c0 = (bid & 127) * 32, half = bid >> 7;
        {   // build A[64][128] from emb (stack+reshape quirk)
            int row = tid >> 2, seg = tid & 3;
            int b = 2 * (row & 3) + half, nd = row >> 2;
            const float4* src = (const float4*)(p.emb + (b * 16 + nd) * 128 + seg * 32);
            u32* dst = (u32*)&Alds[row][seg * 32];
            #pragma unroll
            for (int t = 0; t < 8; ++t) {
                float4 f = src[t];
                dst[2 * t]     = pack2(f.x, f.y);
                dst[2 * t + 1] = pack2(f.z, f.w);
            }
        }
        {   // stage W1 chunk transposed bf16
            int cb = wv * 8;
            const float* s0 = p.W1 + (size_t)(half * 128 + 2 * lane) * 4096 + c0 + cb;
            float4 r0a = ((const float4*)s0)[0], r0b = ((const float4*)s0)[1];
            const float* s1 = s0 + 4096;
            float4 r1a = ((const float4*)s1)[0], r1b = ((const float4*)s1)[1];
            u32* wb = (u32*)&Wlds[0][0];
            wb[(cb + 0) * 68 + lane] = pack2(r0a.x, r1a.x);
            wb[(cb + 1) * 68 + lane] = pack2(r0a.y, r1a.y);
            wb[(cb + 2) * 68 + lane] = pack2(r0a.z, r1a.z);
            wb[(cb + 3) * 68 + lane] = pack2(r0a.w, r1a.w);
            wb[(cb + 4) * 68 + lane] = pack2(r0b.x, r1b.x);
            wb[(cb + 5) * 68 + lane] = pack2(r0b.y, r1b.y);
            wb[(cb + 6) * 68 + lane] = pack2(r0b.z, r1b.z);
            wb[(cb + 7) * 68 + lane] = pack2(r0b.w, r1b.w);
        }
        __syncthreads();
        f32x4 acc0 = {0.f,0.f,0.f,0.f}, acc1 = {0.f,0.f,0.f,0.f};
        #pragma unroll
        for (int ks = 0; ks < 4; ++ks) {
            int kk = ks * 32 + g * 8;
            short8 a8 = *(const short8*)&Alds[wv * 16 + c][kk];
            short8 b0 = *(const short8*)&Wlds[c][kk];
            short8 b1 = *(const short8*)&Wlds[16 + c][kk];
            acc0 = __builtin_amdgcn_mfma_f32_16x16x32_bf16(a8, b0, acc0, 0, 0, 0);
            acc1 = __builtin_amdgcn_mfma_f32_16x16x32_bf16(a8, b1, acc1, 0, 0, 0);
        }
        float* out = p.Cp + (size_t)half * 262144;
        int rbase = wv * 16 + g * 4;
        #pragma unroll
        for (int rr = 0; rr < 4; ++rr) {
            out[(size_t)(rbase + rr) * 4096 + c0 + c]      = acc0[rr];
            out[(size_t)(rbase + rr) * 4096 + c0 + 16 + c] = acc1[rr];
        }
        __syncthreads();
    }
    grid.sync();

    // ---- P1: L1 reduce (ksplit=2) -> Ha bf16   (1024*256 threads == 262144)
    {
        int idx = bid * 256 + tid;
        int col = idx & 4095;
        float s = p.b1[col] + p.Cp[idx] + p.Cp[262144 + idx];
        s = (s >= 0.f) ? s : 0.01f * s;
        p.Ha[idx] = f2bf(s);
    }
    grid.sync();

    // ---- P2: L2 GEMM, 128 col-tiles x 8 k-slices (kchunk=512)
    gemm_slice(p.Ha, p.W2, p.Cp + (size_t)(bid >> 7) * 262144,
               4096, 4096, (bid & 127) * 32, (bid >> 7) * 512, 4, Alds, Wlds, tid);
    grid.sync();

    // ---- P3: L2 reduce (ksplit=8) -> Hb
    {
        int idx = bid * 256 + tid;
        int col = idx & 4095;
        float s = p.b2[col];
        #pragma unroll
        for (int k = 0; k < 8; ++k) s += p.Cp[(size_t)k * 262144 + idx];
        s = (s >= 0.f) ? s : 0.01f * s;
        p.Hb[idx] = f2bf(s);
    }
    grid.sync();

    // ---- P4: L3 GEMM
    gemm_slice(p.Hb, p.W3, p.Cp + (size_t)(bid >> 7) * 262144,
               4096, 4096, (bid & 127) * 32, (bid >> 7) * 512, 4, Alds, Wlds, tid);
    grid.sync();

    // ---- P5: L3 reduce -> Ha
    {
        int idx = bid * 256 + tid;
        int col = idx & 4095;
        float s = p.b3[col];
        #pragma unroll
        for (int k = 0; k < 8; ++k) s += p.Cp[(size_t)k * 262144 + idx];
        s = (s >= 0.f) ? s : 0.01f * s;
        p.Ha[idx] = f2bf(s);
    }
    grid.sync();

    // ---- P6: L4 GEMM, 8 col-tiles x 32 k-slices (kchunk=128) -> Cp[32][64][256]
    if (bid < 256)
        gemm_slice(p.Ha, p.W4, p.Cp + (size_t)(bid >> 3) * 16384,
                   4096, 256, (bid & 7) * 32, (bid >> 3) * 128, 1, Alds, Wlds, tid);
    grid.sync();

    // ---- P7: blocks 0..3: reduce+sigmoid 16 matrices each, 50 DPP power iters
    if (bid < 4) {
        float* pol_lds = (float*)&Alds[0][0];   // 16 KB
        {
            int lr = tid >> 4;                  // local row/matrix 0..15
            int gr = (bid << 4) + lr;           // global matrix
            int cb4 = (tid & 15) << 4;          // 16-col stripe
            float accv[16];
            #pragma unroll
            for (int j = 0; j < 16; ++j) accv[j] = p.b4[cb4 + j];
            for (int k = 0; k < 32; ++k) {
                const float4* q = (const float4*)(p.Cp + (size_t)k * 16384 + gr * 256 + cb4);
                #pragma unroll
                for (int j = 0; j < 4; ++j) {
                    float4 v = q[j];
                    accv[4*j+0] += v.x; accv[4*j+1] += v.y;
                    accv[4*j+2] += v.z; accv[4*j+3] += v.w;
                }
            }
            #pragma unroll
            for (int j = 0; j < 16; ++j) {
                float a = accv[j];
                a = (a >= 0.f) ? a : 0.01f * a;
                pol_lds[lr * 256 + cb4 + j] = 1.0f / (1.0f + __expf(-a));
            }
        }
        __syncthreads();
        // gather row with DPP-rotated index (matches va rotation direction)
        float Mr[8], Ms[8];
        {
            int mb = (tid >> 4) * 256 + (tid & 15) * 16;
            int idx = tid & 15;
            #pragma unroll
            for (int k = 0; k < 8; ++k) { Mr[k] = pol_lds[mb + idx]; idx = dppi<ROR1>(idx); }
            #pragma unroll
            for (int k = 0; k < 8; ++k) { Ms[k] = pol_lds[mb + idx]; idx = dppi<ROR1>(idx); }
        }
        float v = 1.0f;
        #pragma unroll 1
        for (int it = 0; it < 50; ++it) {
            float va = v, vb = dppf<ROR8>(v);
            float w = 0.f, w2 = 0.f;
            #pragma unroll
            for (int k = 0; k < 8; ++k) {
                w  = fmaf(Mr[k], va, w);
                w2 = fmaf(Ms[k], vb, w2);
                if (k < 7) { va = dppf<ROR1>(va); vb = dppf<ROR1>(vb); }
            }
            w += w2;
            if ((it & 7) == 7) {   // positive-sum renorm; scale cancels in output
                float s = w;
                s += dppf<ROR8>(s); s += dppf<ROR4>(s);
                s += dppf<ROR2>(s); s += dppf<ROR1>(s);
                w *= 1.0f / s;
            }
            v = w;
        }
        p.wvec[((bid << 4) + (tid >> 4)) * 16 + (tid & 15)] = v;
        __syncthreads();
    }
    grid.sync();

    // ---- P8: block 0: factored output reduction
    if (bid == 0) {
        float* w_lds  = (float*)&Alds[0][0];    // 4096 B
        float* Ts_lds = (float*)&Wlds[0][0];    // 8192 B
        float* Cmat   = Ts_lds + 2048;          //  512 B (total 8704 == Wlds)
        ((float4*)w_lds)[tid]        = ((const float4*)p.wvec)[tid];
        ((float4*)Ts_lds)[tid]       = ((const float4*)p.Ts)[tid];
        ((float4*)Ts_lds)[256 + tid] = ((const float4*)p.Ts)[256 + tid];
        __syncthreads();
        if (tid < 128) {
            int b = tid >> 4, x = tid & 15;
            float s = 0.f;
            if (b < 4) {
                #pragma unroll
                for (int t = 0; t < 16; ++t) s += Ts_lds[(b * 16 + x) * 16 + t];
            } else {
                int j = b - 4;
                #pragma unroll
                for (int si = 0; si < 16; ++si)
                    s += Ts_lds[(b * 16 + si) * 16 + x] / w_lds[(x * 4 + j) * 16 + si];
            }
            Cmat[b * 16 + x] = s;
        }
        __syncthreads();
        if (tid < 128) {
            int b = tid >> 4, n = tid & 15;
            float o = 0.f;
            if (b < 4) {
                #pragma unroll
                for (int si = 0; si < 16; ++si) {
                    const float* wr = &w_lds[(si * 4 + b) * 16];
                    o += wr[n] / wr[si] * Cmat[b * 16 + si];
                }
            } else {
                int j = b - 4;
                #pragma unroll
                for (int t = 0; t < 16; ++t)
                    o += w_lds[(t * 4 + j) * 16 + n] * Cmat[b * 16 + t];
            }
            p.out[b * 16 + n] = o;
        }
    }
}

// ===========================================================================
// Fallback path (round-3 proven multi-kernel chain), used only if the
// cooperative launch can't run (capacity or capture refusal).
// ===========================================================================
__global__ __launch_bounds__(256) void k_gemm(
    const u16* __restrict__ A, const float* __restrict__ W,
    float* __restrict__ Cp, int K, int N, int kchunk)
{
    __shared__ __align__(16) u16 Alds[64][136];
    __shared__ __align__(16) u16 Wlds[32][136];
    int tid = threadIdx.x;
    gemm_slice(A, W, Cp + (size_t)blockIdx.y * 64 * N, K, N,
               blockIdx.x * 32, blockIdx.y * kchunk, kchunk / 128, Alds, Wlds, tid);
}

__global__ __launch_bounds__(256) void k_gemm_l1(
    const float* __restrict__ emb, const float* __restrict__ W,
    float* __restrict__ Cp)
{
    __shared__ __align__(16) u16 Alds[64][136];
    __shared__ __align__(16) u16 Wlds[32][136];
    int tid = threadIdx.x;
    int wv = tid >> 6, lane = tid & 63, c = lane & 15, g = lane >> 4;
    int c0 = blockIdx.x * 32;
    int half = blockIdx.y;
    {
        int row = tid >> 2, seg = tid & 3;
        int b = 2 * (row & 3) + half, nd = row >> 2;
        const float4* src = (const float4*)(emb + (b * 16 + nd) * 128 + seg * 32);
        u32* dst = (u32*)&Alds[row][seg * 32];
        #pragma unroll
        for (int t = 0; t < 8; ++t) {
            float4 f = src[t];
            dst[2 * t]     = pack2(f.x, f.y);
            dst[2 * t + 1] = pack2(f.z, f.w);
        }
    }
    {
        int cb = wv * 8;
        const float* s0 = W + (size_t)(half * 128 + 2 * lane) * 4096 + c0 + cb;
        float4 r0a = ((const float4*)s0)[0], r0b = ((const float4*)s0)[1];
        const float* s1 = s0 + 4096;
        float4 r1a = ((const float4*)s1)[0], r1b = ((const float4*)s1)[1];
        u32* wb = (u32*)&Wlds[0][0];
        wb[(cb + 0) * 68 + lane] = pack2(r0a.x, r1a.x);
        wb[(cb + 1) * 68 + lane] = pack2(r0a.y, r1a.y);
        wb[(cb + 2) * 68 + lane] = pack2(r0a.z, r1a.z);
        wb[(cb + 3) * 68 + lane] = pack2(r0a.w, r1a.w);
        wb[(cb + 4) * 68 + lane] = pack2(r0b.x, r1b.x);
        wb[(cb + 5) * 68 + lane] = pack2(r0b.y, r1b.y);
        wb[(cb + 6) * 68 + lane] = pack2(r0b.z, r1b.z);
        wb[(cb + 7) * 68 + lane] = pack2(r0b.w, r1b.w);
    }
    __syncthreads();
    f32x4 acc0 = {0.f,0.f,0.f,0.f}, acc1 = {0.f,0.f,0.f,0.f};
    #pragma unroll
    for (int ks = 0; ks < 4; ++ks) {
        int kk = ks * 32 + g * 8;
        short8 a8 = *(const short8*)&Alds[wv * 16 + c][kk];
        short8 b0 = *(const short8*)&Wlds[c][kk];
        short8 b1 = *(const short8*)&Wlds[16 + c][kk];
        acc0 = __builtin_amdgcn_mfma_f32_16x16x32_bf16(a8, b0, acc0, 0, 0, 0);
        acc1 = __builtin_amdgcn_mfma_f32_16x16x32_bf16(a8, b1, acc1, 0, 0, 0);
    }
    float* out = Cp + (size_t)half * 64 * 4096;
    int rbase = wv * 16 + g * 4;
    #pragma unroll
    for (int rr = 0; rr < 4; ++rr) {
        out[(size_t)(rbase + rr) * 4096 + c0 + c]      = acc0[rr];
        out[(size_t)(rbase + rr) * 4096 + c0 + 16 + c] = acc1[rr];
    }
}

__global__ void k_reduce(const float* __restrict__ Cp, const float* __restrict__ bias,
                         u16* __restrict__ Hb, float* __restrict__ Pf,
                         int N, int ksplit, int mode)
{
    int idx = blockIdx.x * 256 + threadIdx.x;
    int col = idx & (N - 1);
    float s = bias[col];
    for (int k = 0; k < ksplit; ++k) s += Cp[(size_t)k * 64 * N + idx];
    float a = (s >= 0.f) ? s : 0.01f * s;
    if (mode == 0) Hb[idx] = f2bf(a);
    else           Pf[idx] = 1.0f / (1.0f + __expf(-a));
}

__global__ __launch_bounds__(1024) void k_power_out(
    const float* __restrict__ pol, const float* __restrict__ Ts,
    float* __restrict__ out)
{
    __shared__ float pol_lds[16384];
    __shared__ float w_lds[64][16];
    __shared__ float Ts_lds[2048];
    __shared__ float Cmat[8][16];
    int tid = threadIdx.x;
    int m = tid >> 4, r = tid & 15;
    {
        const float4* p4 = (const float4*)(pol + tid * 16);
        float4* q4 = (float4*)&pol_lds[tid * 16];
        q4[0] = p4[0]; q4[1] = p4[1]; q4[2] = p4[2]; q4[3] = p4[3];
    }
    Ts_lds[tid] = Ts[tid];
    Ts_lds[tid + 1024] = Ts[tid + 1024];
    __syncthreads();
    float Mr[8], Ms[8];
    {
        int mb = m * 256 + r * 16;
        int idx = r;
        #pragma unroll
        for (int k = 0; k < 8; ++k) { Mr[k] = pol_lds[mb + idx]; idx = dppi<ROR1>(idx); }
        #pragma unroll
        for (int k = 0; k < 8; ++k) { Ms[k] = pol_lds[mb + idx]; idx = dppi<ROR1>(idx); }
    }
    float v = 1.0f;
    #pragma unroll 1
    for (int it = 0; it < 50; ++it) {
        float va = v, vb = dppf<ROR8>(v);
        float w = 0.f, w2 = 0.f;
        #pragma unroll
        for (int k = 0; k < 8; ++k) {
            w  = fmaf(Mr[k], va, w);
            w2 = fmaf(Ms[k], vb, w2);
            if (k < 7) { va = dppf<ROR1>(va); vb = dppf<ROR1>(vb); }
        }
        w += w2;
        if ((it & 7) == 7) {
            float s = w;
            s += dppf<ROR8>(s); s += dppf<ROR4>(s);
            s += dppf<ROR2>(s); s += dppf<ROR1>(s);
            w *= 1.0f / s;
        }
        v = w;
    }
    w_lds[m][r] = v;
    __syncthreads();
    if (tid < 128) {
        int b = tid >> 4, x = tid & 15;
        float s = 0.f;
        if (b < 4) {
            #pragma unroll
            for (int t = 0; t < 16; ++t) s += Ts_lds[(b * 16 + x) * 16 + t];
        } else {
            int j = b - 4;
            #pragma unroll
            for (int si = 0; si < 16; ++si)
                s += Ts_lds[(b * 16 + si) * 16 + x] / w_lds[x * 4 + j][si];
        }
        Cmat[b][x] = s;
    }
    __syncthreads();
    if (tid < 128) {
        int b = tid >> 4, n = tid & 15;
        float o = 0.f;
        if (b < 4) {
            #pragma unroll
            for (int si = 0; si < 16; ++si) {
                const float* wr = w_lds[si * 4 + b];
                o += wr[n] / wr[si] * Cmat[b][si];
            }
        } else {
            int j = b - 4;
            #pragma unroll
            for (int t = 0; t < 16; ++t)
                o += w_lds[t * 4 + j][n] * Cmat[b][t];
        }
        out[b * 16 + n] = o;
    }
}

// ---------------------------------------------------------------------------
extern "C" void kernel_launch(void* const* d_in, const int* in_sizes, int n_in,
                              void* d_out, int out_size, void* d_ws, size_t ws_size,
                              hipStream_t stream)
{
    const float* emb = (const float*)d_in[0];
    const float* Ts  = (const float*)d_in[2];
    const float* W1  = (const float*)d_in[3];  const float* b1 = (const float*)d_in[4];
    const float* W2  = (const float*)d_in[5];  const float* b2 = (const float*)d_in[6];
    const float* W3  = (const float*)d_in[7];  const float* b3 = (const float*)d_in[8];
    const float* W4  = (const float*)d_in[9];  const float* b4 = (const float*)d_in[10];
    float* outp = (float*)d_out;

    char* ws = (char*)d_ws;
    u16*   Ha   = (u16*)(ws + 0);             // 512 KB  [64][4096] bf16
    u16*   Hb   = (u16*)(ws + 524288);        // 512 KB  [64][4096] bf16
    float* Cp   = (float*)(ws + 1048576);     //   8 MB  split-K partials
    float* wvec = (float*)(ws + 9437184);     //   4 KB  [64][16]
    float* pol  = (float*)(ws + 9441280);     //  64 KB  (fallback only)

    MegaP prm { emb, Ts, W1, b1, W2, b2, W3, b3, W4, b4, outp, Ha, Hb, Cp, wvec };

    // capacity pre-check: need >= 4 resident blocks/CU for the 1024-block grid
    int nb = 0;
    hipError_t qe = hipOccupancyMaxActiveBlocksPerMultiprocessor(&nb, (const void*)mega, 256, 0);
    bool coop = (qe == hipSuccess && nb >= 4);
    if (coop) {
        void* args[] = { &prm };
        hipError_t le = hipLaunchCooperativeKernel((const void*)mega, dim3(1024), dim3(256),
                                                   args, 0, stream);
        if (le != hipSuccess) coop = false;
    }
    if (!coop) {   // proven round-3 chain (KS=8 fits the 8 MB Cp region)
        k_gemm_l1<<<dim3(128, 2), 256, 0, stream>>>(emb, W1, Cp);
        k_reduce<<<1024, 256, 0, stream>>>(Cp, b1, Ha, nullptr, 4096, 2, 0);
        k_gemm<<<dim3(128, 8), 256, 0, stream>>>(Ha, W2, Cp, 4096, 4096, 512);
        k_reduce<<<1024, 256, 0, stream>>>(Cp, b2, Hb, nullptr, 4096, 8, 0);
        k_gemm<<<dim3(128, 8), 256, 0, stream>>>(Hb, W3, Cp, 4096, 4096, 512);
        k_reduce<<<1024, 256, 0, stream>>>(Cp, b3, Ha, nullptr, 4096, 8, 0);
        k_gemm<<<dim3(8, 32), 256, 0, stream>>>(Ha, W4, Cp, 4096, 256, 128);
        k_reduce<<<64, 256, 0, stream>>>(Cp, b4, nullptr, pol, 256, 32, 1);
        k_power_out<<<1, 1024, 0, stream>>>(pol, Ts, outp);
    }

    (void)in_sizes; (void)n_in; (void)out_size; (void)ws_size;
}